// Round 8
// baseline (197.789 us; speedup 1.0000x reference)
//
#include <hip/hip_runtime.h>
#include <stdint.h>

#define CNT 8192
#define DIM 128

typedef unsigned long long u64;
typedef unsigned int u32;

// ---- workspace layout (bytes) ----
#define OFF_POS     ((size_t)0)                            // 3*CNT f32
#define OFF_NEG     (OFF_POS + (size_t)3*CNT*4)            // 3*CNT f32
#define OFF_ROWPART (OFF_NEG + (size_t)3*CNT*4)            // 3*64*CNT u32
#define OFF_COLPART (OFF_ROWPART + (size_t)3*64*CNT*4)     // 3*32*CNT u32
#define OFF_RNORM   (OFF_COLPART + (size_t)3*32*CNT*4)     // 6*CNT f32
#define OFF_U       (OFF_RNORM + (size_t)6*CNT*4)          // 6*CNT f32
#define OFF_V       (OFF_U + (size_t)6*CNT*4)              // 6*CNT f32
#define OFF_MPART   (OFF_V + (size_t)6*CNT*4)              // 6144*5 f32
#define OFF_AMEAN   (OFF_MPART + (size_t)6144*5*4)         // 200 f32
#define OFF_AISTD   (OFF_AMEAN + (size_t)1024)             // 200 f32
#define OFF_PSUM    (OFF_AISTD + (size_t)1024)             // 1600 f32
#define OFF_XNB     (OFF_PSUM + (size_t)8192)              // 6*CNT*DIM bf16
// total ~24 MiB

typedef __attribute__((ext_vector_type(8))) short short8;
typedef __attribute__((ext_vector_type(4))) float f32x4;

__device__ __forceinline__ float fract1(float x){
#if __has_builtin(__builtin_amdgcn_fractf)
  return __builtin_amdgcn_fractf(x);
#else
  return x - floorf(x);
#endif
}
__device__ __forceinline__ u32 umax2(u32 a, u32 b){ return a > b ? a : b; }
__device__ __forceinline__ u32 umax3(u32 a, u32 b, u32 c){ u32 t = a > b ? a : b; return t > c ? t : c; }

__device__ __forceinline__ float block_sum(float x, float* red, int tid){
  #pragma unroll
  for (int m=1;m<64;m<<=1) x += __shfl_xor(x, m, 64);
  if ((tid & 63) == 0) red[tid>>6] = x;
  __syncthreads();
  const float r = red[0]+red[1]+red[2]+red[3];
  __syncthreads();
  return r;
}

// row-normalize -> bf16 (A-side segments 0,2,4 pre-scaled by 0.25) + reciprocal norms
__global__ __launch_bounds__(256) void knorm(const float* __restrict__ in,
                                             unsigned int* __restrict__ xnb32,
                                             float* __restrict__ rnorm){
  const int row  = blockIdx.x*4 + (threadIdx.x>>6);
  const int lane = threadIdx.x & 63;
  const float2 v = *(const float2*)(in + (size_t)row*DIM + lane*2);
  float ss = v.x*v.x + v.y*v.y;
  #pragma unroll
  for (int m=1;m<64;m<<=1) ss += __shfl_xor(ss, m, 64);
  const float rn = 1.0f / sqrtf(ss);
  const float sc = ((row & CNT) ? 1.0f : 0.25f) * rn;
  unsigned int ux = __float_as_uint(v.x*sc), uy = __float_as_uint(v.y*sc);
  ux = (ux + 0x7FFFu + ((ux>>16)&1u)) >> 16;
  uy = (uy + 0x7FFFu + ((uy>>16)&1u)) >> 16;
  xnb32[(size_t)row*64 + lane] = ux | (uy<<16);
  if (lane == 0) rnorm[row] = rn;
}

// ---------------- MFMA bf16 GEMM, 256x128 tile, 4 waves x (128x64), BK=32 dbuf ----------------
// acc = dot/4 (A pre-scaled). key = fract(acc): larger key == smaller dm (dm = 1/dot + eps).
// Row pack: [key25 | ~col7]; Col pack: [key24 | ~row8]. u32 max = argmax + lowest-idx ties.
// Global partials: u32 [inv_key19 | index13], min-reduced in kpick.
__global__ __launch_bounds__(256) void kgemm(const unsigned short* __restrict__ xnb,
    u32* __restrict__ rowpart, u32* __restrict__ colpart){
  __shared__ __align__(16) char LB[49152];   // A dbuf 2x16KB @0, B dbuf 2x8KB @32768; epilogue reuse
  const int pair = blockIdx.z;
  const int xo3[3] = {0, 2*CNT, 4*CNT};
  const int yo3[3] = {CNT, 5*CNT, 3*CNT};
  const unsigned short* __restrict__ X = xnb + (size_t)xo3[pair]*DIM;
  const unsigned short* __restrict__ Y = xnb + (size_t)yo3[pair]*DIM;
  const int brow = blockIdx.y*256, bcol = blockIdx.x*128;
  const int tid = threadIdx.x, lane = tid & 63, wid = tid >> 6;
  const int wr = wid >> 1, wc = wid & 1;           // waves: 2 (m, 128 rows) x 2 (n, 64 cols)
  const int lrow = lane & 15, kgrp = lane >> 4;

  // staging sources: A 16x 1KB insts (j=wid*4+t), B 8x (j=wid*2+t); row = j*16 + (lane>>2)
  const int rr16 = lane >> 2;
  const int slog = (lane&3) ^ ((lane>>3)&3);       // logical k-slot this phys slot holds
  const unsigned short* gA[4];
  #pragma unroll
  for (int t=0;t<4;t++) gA[t] = X + (size_t)(brow + (wid*4+t)*16 + rr16)*DIM + slog*8;
  const unsigned short* gB[2];
  #pragma unroll
  for (int t=0;t<2;t++) gB[t] = Y + (size_t)(bcol + (wid*2+t)*16 + rr16)*DIM + slog*8;

#define STAGEC(c) do{ \
    char* LA_ = LB + ((c)&1)*16384; \
    char* LB_ = LB + 32768 + ((c)&1)*8192; \
    __builtin_amdgcn_global_load_lds((const __attribute__((address_space(1))) void*)(gA[0] + (c)*32), \
        (__attribute__((address_space(3))) void*)(LA_ + (wid*4+0)*1024), 16, 0, 0); \
    __builtin_amdgcn_global_load_lds((const __attribute__((address_space(1))) void*)(gA[1] + (c)*32), \
        (__attribute__((address_space(3))) void*)(LA_ + (wid*4+1)*1024), 16, 0, 0); \
    __builtin_amdgcn_global_load_lds((const __attribute__((address_space(1))) void*)(gA[2] + (c)*32), \
        (__attribute__((address_space(3))) void*)(LA_ + (wid*4+2)*1024), 16, 0, 0); \
    __builtin_amdgcn_global_load_lds((const __attribute__((address_space(1))) void*)(gA[3] + (c)*32), \
        (__attribute__((address_space(3))) void*)(LA_ + (wid*4+3)*1024), 16, 0, 0); \
    __builtin_amdgcn_global_load_lds((const __attribute__((address_space(1))) void*)(gB[0] + (c)*32), \
        (__attribute__((address_space(3))) void*)(LB_ + (wid*2+0)*1024), 16, 0, 0); \
    __builtin_amdgcn_global_load_lds((const __attribute__((address_space(1))) void*)(gB[1] + (c)*32), \
        (__attribute__((address_space(3))) void*)(LB_ + (wid*2+1)*1024), 16, 0, 0); \
  }while(0)

  f32x4 acc[8][4];
  #pragma unroll
  for (int m=0;m<8;m++)
    #pragma unroll
    for (int n=0;n<4;n++)
      acc[m][n] = (f32x4){0.f,0.f,0.f,0.f};

  STAGEC(0);
  __syncthreads();

  const int kb = (kgrp*16) ^ (((lrow>>1)&3) << 4);
  #pragma unroll
  for (int c=0;c<4;c++){
    if (c<3) STAGEC(c+1);
    const char* bA = LB + (c&1)*16384 + (wr*128 + lrow)*64 + kb;
    const char* bB = LB + 32768 + (c&1)*8192 + (wc*64 + lrow)*64 + kb;
    short8 bv[4];
    #pragma unroll
    for (int n=0;n<4;n++) bv[n] = *(const short8*)(bB + n*1024);
    #pragma unroll
    for (int m=0;m<8;m++){
      const short8 av = *(const short8*)(bA + m*1024);
      #pragma unroll
      for (int n=0;n<4;n++)
        acc[m][n] = __builtin_amdgcn_mfma_f32_16x16x32_bf16(av, bv[n], acc[m][n], 0, 0, 0);
    }
    if (c<3) __syncthreads();
  }

  // diagonal: acc=0 -> key 0 = minimal (reference adds BIG). Diag blocks: bx>>1 == by.
  if ((blockIdx.x >> 1) == blockIdx.y && wr == (int)(blockIdx.x & 1) && kgrp == (lrow >> 2)){
    #pragma unroll
    for (int r=0;r<4;r++)
      if ((lrow & 3) == r){
        if (wc == 0){
          #pragma unroll
          for (int n=0;n<4;n++) acc[n][n][r] = 0.0f;
        } else {
          #pragma unroll
          for (int n=0;n<4;n++) acc[4+n][n][r] = 0.0f;
        }
      }
  }

  __syncthreads();                                  // tiles consumed; reuse LDS for epilogue
  u32* rowbuf = (u32*)LB;                           // [256][36] u32 = 36.9KB
  u32* colred = (u32*)(LB + 40960);                 // [2][128] u32 = 1KB

  // packing + max-trees; row candidates written straight to LDS (keeps VGPR down)
  const int colb_loc = wc*64 + lrow;
  u32 orvr[4];
  #pragma unroll
  for (int n=0;n<4;n++) orvr[n] = (u32)(127 - colb_loc - n*16);
  const int rowbase = wr*128 + kgrp*4;              // + m*16 + r = local row (8-bit)
  const int slot = wc*16 + lrow;
  u32 pkc[4] = {0u,0u,0u,0u};
  #pragma unroll
  for (int m=0;m<8;m++){
    #pragma unroll
    for (int r=0;r<4;r++){
      const int rowloc = rowbase + m*16 + r;
      const u32 orvc = (u32)(255 - rowloc);
      u32 kb2[4];
      #pragma unroll
      for (int n=0;n<4;n++)
        kb2[n] = __float_as_uint(fract1(acc[m][n][r]));
      const u32 b0 = (kb2[0] & 0xFFFFFF80u) | orvr[0];
      const u32 b1 = (kb2[1] & 0xFFFFFF80u) | orvr[1];
      const u32 b2 = (kb2[2] & 0xFFFFFF80u) | orvr[2];
      const u32 b3 = (kb2[3] & 0xFFFFFF80u) | orvr[3];
      rowbuf[rowloc*36 + slot] = umax2(umax3(b0, b1, b2), b3);
      pkc[0] = umax2(pkc[0], (kb2[0] & 0xFFFFFF00u) | orvc);
      pkc[1] = umax2(pkc[1], (kb2[1] & 0xFFFFFF00u) | orvc);
      pkc[2] = umax2(pkc[2], (kb2[2] & 0xFFFFFF00u) | orvc);
      pkc[3] = umax2(pkc[3], (kb2[3] & 0xFFFFFF00u) | orvc);
    }
  }

  // col: combine across kgrp lanes (row id embedded -> shuffle-max keeps winner)
  #pragma unroll
  for (int n=0;n<4;n++){
    u32 o = (u32)__shfl_xor((int)pkc[n], 16, 64); pkc[n] = umax2(pkc[n], o);
    o = (u32)__shfl_xor((int)pkc[n], 32, 64);     pkc[n] = umax2(pkc[n], o);
  }
  if (kgrp == 0){
    #pragma unroll
    for (int n=0;n<4;n++)
      colred[wr*128 + wc*64 + n*16 + lrow] = pkc[n];
  }
  __syncthreads();

  {  // row final: every thread reduces one of the 256 rows (32 candidates)
    const u32* base = rowbuf + tid*36;
    u32 best = 0u;
    #pragma unroll
    for (int q=0;q<8;q++){
      const uint4 t = *(const uint4*)(base + q*4);
      best = umax2(best, umax2(umax3(t.x, t.y, t.z), t.w));
    }
    const int colg = 127 - (int)(best & 127u);
    rowpart[((size_t)pair*64 + blockIdx.x)*CNT + (brow + tid)] =
        ((~best) & 0xFFFFE000u) | (u32)(bcol + colg);
  }
  if (tid < 128){
    const u32 a0 = colred[tid], a1 = colred[128 + tid];
    const u32 w = umax2(a0, a1);
    const int rloc = 255 - (int)(w & 255u);
    colpart[((size_t)pair*32 + blockIdx.y)*CNT + (bcol + tid)] =
        ((~w) & 0xFFFFE000u) | (u32)(brow + rloc);
  }
#undef STAGEC
}

// fused: reduce row (64) / col (32) partials + pick hard negative + dots via rnorm + u,v + moments
__global__ __launch_bounds__(256) void kpick(const float* __restrict__ descs,
    const float* __restrict__ rnorm,
    const u32* __restrict__ rowpart, const u32* __restrict__ colpart,
    float* __restrict__ pos, float* __restrict__ neg,
    float* __restrict__ u, float* __restrict__ v, float* __restrict__ mpart){
  __shared__ float sred[4][5];
  const int tid = threadIdx.x;
  const int w4 = tid >> 6, lane = tid & 63;
  const int e = blockIdx.x*4 + w4;                 // 0..24575
  const int p = e >> 13, i = e & (CNT-1);
  const int xo[3] = {0, 2*CNT, 4*CNT};
  const int yo[3] = {CNT, 5*CNT, 3*CNT};
  u32 rv = rowpart[((size_t)p*64 + lane)*CNT + i];
  u32 cv = (lane < 32) ? colpart[((size_t)p*32 + lane)*CNT + i] : 0xFFFFFFFFu;
  #pragma unroll
  for (int m=1;m<64;m<<=1){
    u32 o = (u32)__shfl_xor((int)rv, m, 64); rv = o < rv ? o : rv;
    o = (u32)__shfl_xor((int)cv, m, 64);     cv = o < cv ? o : cv;
  }
  int orow;
  if ((rv & 0xFFFFE000u) < (cv & 0xFFFFE000u)) orow = yo[p] + (int)(rv & 0x1FFFu);
  else                                          orow = xo[p] + (int)(cv & 0x1FFFu);
  const float2 va = *(const float2*)(descs + (size_t)(xo[p]+i)*DIM + lane*2);
  const float2 vp = *(const float2*)(descs + (size_t)(yo[p]+i)*DIM + lane*2);
  const float2 vn = *(const float2*)(descs + (size_t)orow*DIM + lane*2);
  float sap = va.x*vp.x + va.y*vp.y;
  float san = va.x*vn.x + va.y*vn.y;
  #pragma unroll
  for (int m=1;m<64;m<<=1){
    sap += __shfl_xor(sap, m, 64);
    san += __shfl_xor(san, m, 64);
  }
  if (lane == 0){
    const float rna = rnorm[xo[p]+i];
    const float dp = sap * rna * rnorm[yo[p]+i];
    const float dn = san * rna * rnorm[orow];
    pos[p*CNT + i] = dp; neg[p*CNT + i] = dn;
    const float omp_ = 1.f - dp, sqp = sqrtf(2.f*omp_ + 1e-12f), up = omp_ - sqp;
    const float omn_ = 1.f - dn, sqn = sqrtf(2.f*omn_ + 1e-12f), un = omn_ - sqn;
    u[p*CNT + i] = up;           v[p*CNT + i] = sqp;
    u[3*CNT + p*CNT + i] = un;   v[3*CNT + p*CNT + i] = sqn;
    const float cup = up + 0.35f, cvp = sqp - 0.80f;
    const float cun = un + 0.35f, cvn = sqn - 0.80f;
    sred[w4][0] = up + un;
    sred[w4][1] = sqp + sqn;
    sred[w4][2] = cup*cup + cun*cun;
    sred[w4][3] = cup*cvp + cun*cvn;
    sred[w4][4] = cvp*cvp + cvn*cvn;
  }
  __syncthreads();
  if (tid < 5)
    mpart[blockIdx.x*5 + tid] = sred[0][tid] + sred[1][tid] + sred[2][tid] + sred[3][tid];
}

// combine moment partials; per-alpha mean & inv_std
__global__ __launch_bounds__(256) void kmom(const float* __restrict__ mpart,
    float* __restrict__ amean, float* __restrict__ aistd){
  __shared__ float red[4];
  __shared__ float sm[5];
  const int tid = threadIdx.x;
  float a0=0.f,a1=0.f,a2=0.f,a3=0.f,a4=0.f;
  for (int i = tid; i < 6144; i += 256){
    const float* mp = mpart + (size_t)i*5;
    a0+=mp[0]; a1+=mp[1]; a2+=mp[2]; a3+=mp[3]; a4+=mp[4];
  }
  a0 = block_sum(a0, red, tid);
  a1 = block_sum(a1, red, tid);
  a2 = block_sum(a2, red, tid);
  a3 = block_sum(a3, red, tid);
  a4 = block_sum(a4, red, tid);
  if (tid == 0){ sm[0]=a0; sm[1]=a1; sm[2]=a2; sm[3]=a3; sm[4]=a4; }
  __syncthreads();
  const float N = 49152.0f;
  const float mu_u = sm[0]/N, mu_v = sm[1]/N;
  const float du = mu_u + 0.35f, dv = mu_v - 0.80f;
  const float Suu = sm[2] - N*du*du;
  const float Suv = sm[3] - N*du*dv;
  const float Svv = sm[4] - N*dv*dv;
  if (tid < 200){
    const float a = -1.0f + 0.01f*(float)tid;
    amean[tid] = a*mu_u + mu_v;
    const float var = (a*a*Suu + 2.0f*a*Suv + Svv) / 49151.0f;
    aistd[tid] = 1.0f/sqrtf(var);
  }
}

// kbce: grid (200 alphas x 8 chunks); fast softplus partial sums
__global__ __launch_bounds__(256) void kbce(const float* __restrict__ u, const float* __restrict__ v,
    const float* __restrict__ amean, const float* __restrict__ aistd, float* __restrict__ psum){
  __shared__ float red[4];
  const int tid = threadIdx.x;
  const int a = blockIdx.x >> 3, c = blockIdx.x & 7;
  const float av = -1.0f + 0.01f*(float)a;
  const float mean = amean[a], istd = aistd[a];
  const int base = c*6144;
  float s = 0.0f;
  #pragma unroll 4
  for (int k = 0; k < 24; ++k){
    const int idx = base + k*256 + tid;
    const float z = (fmaf(av, u[idx], v[idx]) - mean) * istd;
    const float zz = (idx < 3*CNT) ? z : -z;
    s += fmaxf(zz, 0.0f) + __logf(1.0f + __expf(-fabsf(zz)));
  }
  s = block_sum(s, red, tid);
  if (tid == 0) psum[blockIdx.x] = s;
}

// argmin(bce) -> alpha; losses, mask ratio, l_mean; 8 outputs
__global__ __launch_bounds__(256) void kfinal(const float* __restrict__ pos, const float* __restrict__ neg,
    const float* __restrict__ psum, const float* __restrict__ l_a_adv, const float* __restrict__ l_p_adv,
    float* __restrict__ out){
  __shared__ float sbce[200];
  __shared__ float sal[2];
  __shared__ float red[4];
  const int tid = threadIdx.x;
  if (tid < 200){
    float s = 0.f;
    #pragma unroll
    for (int c=0;c<8;c++) s += psum[tid*8 + c];
    sbce[tid] = s;
  }
  __syncthreads();
  if (tid == 0){
    float best = sbce[0]; int bk = 0;
    for (int k=1;k<200;k++){
      const float vv = sbce[k];
      if (vv < best){ best = vv; bk = k; }
    }
    const float aopt = -1.0f + 0.01f*(float)bk;
    sal[0] = aopt;
    sal[1] = aopt * 0.005f;
  }
  __syncthreads();
  const float alpha = sal[1];

  float sc=0.f, sar=0.f, saa=0.f, sm=0.f, sla=0.f, slp=0.f;
  for (int i = tid; i < CNT; i += 256){
    const float pap = pos[i],        nap = neg[i];
    const float par = pos[CNT+i],    nar = neg[CNT+i];
    const float paa = pos[2*CNT+i],  naa = neg[2*CNT+i];
    const float cp = fminf(fmaxf(pap, -1.0f), 1.0f);
    const float cn = fminf(fmaxf(nap, -1.0f), 1.0f);
    const float m = (0.36f + acosf(cp) - acosf(cn) > 0.0f) ? 1.0f : 0.0f;
    #define DDIST(d) (alpha*(1.0f-(d)) + (1.0f-alpha)*sqrtf(2.0f*(1.0f-(d)) + 1e-12f))
    sc  += (DDIST(pap) - DDIST(nap)) * m;
    sar += (l_p_adv[i]*DDIST(par) - DDIST(nar)) * m;
    saa += (l_a_adv[i]*DDIST(paa) - DDIST(naa)) * m;
    sm  += m;
    sla += l_a_adv[i];
    slp += l_p_adv[i];
  }
  float vals[6] = {sc, sar, saa, sm, sla, slp};
  float tot[6];
  for (int vv=0; vv<6; vv++){
    tot[vv] = block_sum(vals[vv], red, tid);
  }
  if (tid == 0){
    const float lc  = tot[0] / (float)CNT;
    const float lar = tot[1] / (float)CNT;
    const float laa = tot[2] / (float)CNT;
    out[0] = (lc + lar + laa) / 3.0f;
    out[1] = lc;
    out[2] = lar;
    out[3] = laa;
    out[4] = (tot[4]/(float)CNT + tot[5]/(float)CNT) * 0.5f;
    out[5] = sal[1];
    out[6] = sal[0];
    out[7] = tot[3] / (float)CNT;
  }
}

extern "C" void kernel_launch(void* const* d_in, const int* in_sizes, int n_in,
                              void* d_out, int out_size, void* d_ws, size_t ws_size,
                              hipStream_t stream) {
  const float* descs = (const float*)d_in[0];
  const float* l_a   = (const float*)d_in[1];
  const float* l_p   = (const float*)d_in[2];
  float* out = (float*)d_out;
  char* ws = (char*)d_ws;

  float* pos = (float*)(ws + OFF_POS);
  float* neg = (float*)(ws + OFF_NEG);
  u32* rowpart = (u32*)(ws + OFF_ROWPART);
  u32* colpart = (u32*)(ws + OFF_COLPART);
  float* rnorm = (float*)(ws + OFF_RNORM);
  float* u     = (float*)(ws + OFF_U);
  float* v     = (float*)(ws + OFF_V);
  float* mpart = (float*)(ws + OFF_MPART);
  float* amean = (float*)(ws + OFF_AMEAN);
  float* aistd = (float*)(ws + OFF_AISTD);
  float* psum  = (float*)(ws + OFF_PSUM);
  unsigned int* xnb32 = (unsigned int*)(ws + OFF_XNB);
  const unsigned short* xnb = (const unsigned short*)(ws + OFF_XNB);

  knorm  <<<(6*CNT)/4, 256, 0, stream>>>(descs, xnb32, rnorm);
  kgemm  <<<dim3(64,32,3), 256, 0, stream>>>(xnb, rowpart, colpart);
  kpick  <<<(3*CNT)/4, 256, 0, stream>>>(descs, rnorm, rowpart, colpart, pos, neg, u, v, mpart);
  kmom   <<<1, 256, 0, stream>>>(mpart, amean, aistd);
  kbce   <<<1600, 256, 0, stream>>>(u, v, amean, aistd, psum);
  kfinal <<<1, 256, 0, stream>>>(pos, neg, psum, l_a, l_p, out);
}